// Round 12
// baseline (463.845 us; speedup 1.0000x reference)
//
#include <hip/hip_runtime.h>

#define N_ATOMS 262144
#define N_PAIRS 16777216
#define FCOMP (N_ATOMS * 3)

#define NB      256            // buckets (atom >> 10)
#define BSHIFT  10
#define ALOCAL  (N_ATOMS / NB) // 1024 atoms per bucket
#define CAPBB   32             // record slots per (block,bucket)
#define SC_THREADS 128         // 2 waves
#define NPT     32             // pairs per scatter thread
#define PPB     (SC_THREADS * NPT)   // 4096 pairs per scatter block
#define G_TOTAL (N_PAIRS / PPB)      // 4096 scatter blocks total
#define STG     4              // pairs per thread per stage
#define NSTG    (NPT / STG)    // 8 stages
#define ACC_THREADS 1024

typedef int          v4i __attribute__((ext_vector_type(4)));
typedef float        v4f __attribute__((ext_vector_type(4)));
typedef unsigned int u32;
typedef u32          v4u __attribute__((ext_vector_type(4)));

__device__ __forceinline__ void atomic_add_f32(float* addr, float v) {
    unsafeAtomicAdd(addr, v);
}
__device__ __forceinline__ float scrub_nonfinite(float x) {
    return ((__float_as_uint(x) & 0x7f800000u) == 0x7f800000u) ? 0.0f : x;
}

// prep: pad positions to float4, zero forces + energy accumulator.
__global__ void __launch_bounds__(256) lj_prep_kernel(
    const float* __restrict__ pos, v4f* __restrict__ pos4,
    float* __restrict__ forces, double* __restrict__ ews)
{
    const int a = blockIdx.x * blockDim.x + threadIdx.x;
    if (a < N_ATOMS) {
        v4f p = {pos[3 * a + 0], pos[3 * a + 1], pos[3 * a + 2], 0.0f};
        pos4[a] = p;
        forces[3 * a + 0] = 0.0f;
        forces[3 * a + 1] = 0.0f;
        forces[3 * a + 2] = 0.0f;
    }
    if (a == 0) *ews = 0.0;
}

// ---------- scatter: gathers via global_load_lds (zero-VGPR, un-sinkable) ----------
__global__ void __launch_bounds__(SC_THREADS) lj_scatter_kernel(
    const v4f* __restrict__ pos4,
    const float* __restrict__ cell,
    const int* __restrict__ map_i,
    const int* __restrict__ map_j,
    const float* __restrict__ shifts,
    v4u* __restrict__ records,
    u32* __restrict__ cnts,
    int pair_base, int g_count,
    double* __restrict__ energy_ws)
{
    // [dbuf][wave][slot(2*STG)][lane] — 2*2*8*64*16B = 32 KB
    __shared__ v4f stage_lds[2][SC_THREADS / 64][2 * STG][64];
    __shared__ u32 hist[NB];
    __shared__ double wave_sums[SC_THREADS / 64];

    const int tid  = threadIdx.x;
    const int g    = blockIdx.x;
    const int wid  = tid >> 6;
    const int lane = tid & 63;
    for (int t = tid; t < NB; t += SC_THREADS) hist[t] = 0;
    __syncthreads();

    const float c00 = cell[0], c01 = cell[1], c02 = cell[2];
    const float c10 = cell[3], c11 = cell[4], c12 = cell[5];
    const float c20 = cell[6], c21 = cell[7], c22 = cell[8];

    double e_acc = 0.0;
    const size_t rec_base = (size_t)g * NB * CAPBB;
    const int base4 = pair_base / 4;
    const v4i* mi4 = (const v4i*)map_i;
    const v4i* mj4 = (const v4i*)map_j;
    const v4f* sh4 = (const v4f*)shifts;

    auto do_pair = [&](int i, int j, const v4f& Pi, const v4f& Pj,
                       float sx, float sy, float sz) {
        const float shx = sx * c00 + sy * c10 + sz * c20;
        const float shy = sx * c01 + sy * c11 + sz * c21;
        const float shz = sx * c02 + sy * c12 + sz * c22;
        const float dx = Pj.x - Pi.x + shx;
        const float dy = Pj.y - Pi.y + shy;
        const float dz = Pj.z - Pi.z + shz;
        const float r2 = dx * dx + dy * dy + dz * dz;
        if (r2 < 6.25f) {
            const float inv_r2 = 1.0f / r2;
            const float sr6  = inv_r2 * inv_r2 * inv_r2;
            const float sr12 = sr6 * sr6;
            e_acc += (double)scrub_nonfinite(4.0f * (sr12 - sr6));
            const float pf = 24.0f * inv_r2 * (2.0f * sr12 - sr6);
            const float fx = scrub_nonfinite(pf * dx);
            const float fy = scrub_nonfinite(pf * dy);
            const float fz = scrub_nonfinite(pf * dz);
            const u32 bi = ((u32)i) >> BSHIFT;
            const u32 bj = ((u32)j) >> BSHIFT;
            const u32 si = atomicAdd(&hist[bi], 1u);
            if (si < CAPBB) {
                v4u ri = {(u32)i, __float_as_uint(-fx), __float_as_uint(-fy), __float_as_uint(-fz)};
                __builtin_nontemporal_store(ri, &records[rec_base + (size_t)bi * CAPBB + si]);
            }
            const u32 sj = atomicAdd(&hist[bj], 1u);
            if (sj < CAPBB) {
                v4u rj = {(u32)j, __float_as_uint(fx), __float_as_uint(fy), __float_as_uint(fz)};
                __builtin_nontemporal_store(rj, &records[rec_base + (size_t)bj * CAPBB + sj]);
            }
        }
    };

// wait all vmem (prev stage's LDS-gathers + idx loads), then fence the scheduler
// so ds_reads of the staged data cannot be hoisted above the wait (rule #18).
#define VM0 asm volatile("s_waitcnt vmcnt(0)" ::: "memory"); \
            __builtin_amdgcn_sched_barrier(0);

#define IDX_DECL(S) v4i mi##S, mj##S; v4f sa##S, sb##S, sc##S;
#define IDX_LOAD(S, t) { \
    const int e_ = base4 + ((t) * g_count + g) * SC_THREADS + tid; \
    mi##S = __builtin_nontemporal_load(mi4 + e_); \
    mj##S = __builtin_nontemporal_load(mj4 + e_); \
    sa##S = __builtin_nontemporal_load(sh4 + 3 * e_ + 0); \
    sb##S = __builtin_nontemporal_load(sh4 + 3 * e_ + 1); \
    sc##S = __builtin_nontemporal_load(sh4 + 3 * e_ + 2); }

// one wave-instruction gathers 64 lanes' 16B positions into contiguous LDS
#define GLDS_ONE(d, slot, atom) \
    __builtin_amdgcn_global_load_lds( \
        (const __attribute__((address_space(1))) void*)(pos4 + (atom)), \
        (__attribute__((address_space(3))) void*)(u32)(uintptr_t)(&stage_lds[d][wid][slot][0]), \
        16, 0, 0);

#define GLDS_STAGE(d, S) \
    GLDS_ONE(d, 0, mi##S.x) GLDS_ONE(d, 1, mj##S.x) \
    GLDS_ONE(d, 2, mi##S.y) GLDS_ONE(d, 3, mj##S.y) \
    GLDS_ONE(d, 4, mi##S.z) GLDS_ONE(d, 5, mj##S.z) \
    GLDS_ONE(d, 6, mi##S.w) GLDS_ONE(d, 7, mj##S.w)

#define COMP_STAGE(d, S) { \
    const v4f Pi0 = stage_lds[d][wid][0][lane]; const v4f Pj0 = stage_lds[d][wid][1][lane]; \
    const v4f Pi1 = stage_lds[d][wid][2][lane]; const v4f Pj1 = stage_lds[d][wid][3][lane]; \
    const v4f Pi2 = stage_lds[d][wid][4][lane]; const v4f Pj2 = stage_lds[d][wid][5][lane]; \
    const v4f Pi3 = stage_lds[d][wid][6][lane]; const v4f Pj3 = stage_lds[d][wid][7][lane]; \
    do_pair(mi##S.x, mj##S.x, Pi0, Pj0, sa##S.x, sa##S.y, sa##S.z); \
    do_pair(mi##S.y, mj##S.y, Pi1, Pj1, sa##S.w, sb##S.x, sb##S.y); \
    do_pair(mi##S.z, mj##S.z, Pi2, Pj2, sb##S.z, sb##S.w, sc##S.x); \
    do_pair(mi##S.w, mj##S.w, Pi3, Pj3, sc##S.y, sc##S.z, sc##S.w); }

    IDX_DECL(A) IDX_DECL(B)
    // prologue: stage 0 gathers in flight, stage 1 idx in flight
    IDX_LOAD(A, 0)
    GLDS_STAGE(0, A)
    IDX_LOAD(B, 1)
    // steady state: while computing stage t, stage t+1's 8 gathers are in flight
    VM0 GLDS_STAGE(1, B) COMP_STAGE(0, A) IDX_LOAD(A, 2)
    VM0 GLDS_STAGE(0, A) COMP_STAGE(1, B) IDX_LOAD(B, 3)
    VM0 GLDS_STAGE(1, B) COMP_STAGE(0, A) IDX_LOAD(A, 4)
    VM0 GLDS_STAGE(0, A) COMP_STAGE(1, B) IDX_LOAD(B, 5)
    VM0 GLDS_STAGE(1, B) COMP_STAGE(0, A) IDX_LOAD(A, 6)
    VM0 GLDS_STAGE(0, A) COMP_STAGE(1, B) IDX_LOAD(B, 7)
    VM0 GLDS_STAGE(1, B) COMP_STAGE(0, A)
    VM0 COMP_STAGE(1, B)

#undef VM0
#undef IDX_DECL
#undef IDX_LOAD
#undef GLDS_ONE
#undef GLDS_STAGE
#undef COMP_STAGE

    __syncthreads();

    // publish per-bucket counts (clamped to capacity)
    for (int t = tid; t < NB; t += SC_THREADS) {
        const u32 c = hist[t];
        cnts[(size_t)g * NB + t] = (c < CAPBB) ? c : (u32)CAPBB;
    }

    // energy reduce
    for (int off = 32; off > 0; off >>= 1)
        e_acc += __shfl_down(e_acc, off, 64);
    if (lane == 0) wave_sums[wid] = e_acc;
    __syncthreads();
    if (tid == 0) {
        double s = 0.0;
        for (int w = 0; w < SC_THREADS / 64; ++w) s += wave_sums[w];
        atomicAdd(energy_ws, s);
    }
}

// ---------- accumulate: block b owns atoms [b*1024, b*1024+1024) ----------
__global__ void __launch_bounds__(ACC_THREADS) lj_accum_kernel(
    const v4u* __restrict__ records,
    const u32* __restrict__ cnts,
    int g_count,
    float* __restrict__ forces)
{
    __shared__ float facc[ALOCAL * 3];   // 12 KB
    __shared__ u32 lcnt[G_TOTAL];        // 16 KB (first g_count used)
    const int b = blockIdx.x;
    const int tid = threadIdx.x;

    for (int t = tid; t < ALOCAL * 3; t += ACC_THREADS) facc[t] = 0.0f;
    for (int t = tid; t < g_count; t += ACC_THREADS) lcnt[t] = cnts[(size_t)t * NB + b];
    __syncthreads();

    const int total = g_count * CAPBB;
    for (int r = tid; r < total; r += ACC_THREADS) {
        const int g = r >> 5;       // CAPBB = 32
        const int k = r & (CAPBB - 1);
        if ((u32)k < lcnt[g]) {
            const v4u rec = __builtin_nontemporal_load(&records[((size_t)g * NB + b) * CAPBB + k]);
            const u32 al = rec.x & (ALOCAL - 1);
            atomicAdd(&facc[al * 3 + 0], __uint_as_float(rec.y));
            atomicAdd(&facc[al * 3 + 1], __uint_as_float(rec.z));
            atomicAdd(&facc[al * 3 + 2], __uint_as_float(rec.w));
        }
    }
    __syncthreads();

    const int fbase = (b << BSHIFT) * 3;
    for (int t = tid; t < ALOCAL * 3; t += ACC_THREADS)
        forces[fbase + t] += facc[t];
}

// ---------- fallback path (proven round-2 style, direct atomics) ----------
__global__ void __launch_bounds__(256) lj_zero_kernel(float* __restrict__ buf, int n,
                                                      double* __restrict__ ews) {
    int idx = blockIdx.x * blockDim.x + threadIdx.x;
    int stride = gridDim.x * blockDim.x;
    for (int k = idx; k < n; k += stride) buf[k] = 0.0f;
    if (idx == 0) *ews = 0.0;
}

__global__ void __launch_bounds__(256) lj_pair_direct_kernel(
    const float* __restrict__ pos,
    const float* __restrict__ cell,
    const int* __restrict__ map_i,
    const int* __restrict__ map_j,
    const float* __restrict__ shifts,
    float* __restrict__ forces,
    double* __restrict__ energy_ws)
{
    const float c00 = cell[0], c01 = cell[1], c02 = cell[2];
    const float c10 = cell[3], c11 = cell[4], c12 = cell[5];
    const float c20 = cell[6], c21 = cell[7], c22 = cell[8];
    double e_acc = 0.0;
    const int t = blockIdx.x * blockDim.x + threadIdx.x;
    const v4i mi = ((const v4i*)map_i)[t];
    const v4i mj = ((const v4i*)map_j)[t];
    const v4f sa = ((const v4f*)shifts)[3 * t + 0];
    const v4f sb = ((const v4f*)shifts)[3 * t + 1];
    const v4f sc = ((const v4f*)shifts)[3 * t + 2];
    auto body = [&](int i, int j, float sx, float sy, float sz) {
        const float shx = sx * c00 + sy * c10 + sz * c20;
        const float shy = sx * c01 + sy * c11 + sz * c21;
        const float shz = sx * c02 + sy * c12 + sz * c22;
        const float dx = pos[3*j]   - pos[3*i]   + shx;
        const float dy = pos[3*j+1] - pos[3*i+1] + shy;
        const float dz = pos[3*j+2] - pos[3*i+2] + shz;
        const float r2 = dx*dx + dy*dy + dz*dz;
        if (r2 < 6.25f) {
            const float inv_r2 = 1.0f / r2;
            const float sr6 = inv_r2*inv_r2*inv_r2, sr12 = sr6*sr6;
            e_acc += (double)scrub_nonfinite(4.0f * (sr12 - sr6));
            const float pf = 24.0f * inv_r2 * (2.0f * sr12 - sr6);
            const float fx = scrub_nonfinite(pf*dx), fy = scrub_nonfinite(pf*dy), fz = scrub_nonfinite(pf*dz);
            atomic_add_f32(&forces[3*i+0], -fx); atomic_add_f32(&forces[3*i+1], -fy); atomic_add_f32(&forces[3*i+2], -fz);
            atomic_add_f32(&forces[3*j+0],  fx); atomic_add_f32(&forces[3*j+1],  fy); atomic_add_f32(&forces[3*j+2],  fz);
        }
    };
    body(mi.x, mj.x, sa.x, sa.y, sa.z);
    body(mi.y, mj.y, sa.w, sb.x, sb.y);
    body(mi.z, mj.z, sb.z, sb.w, sc.x);
    body(mi.w, mj.w, sc.y, sc.z, sc.w);
    for (int off = 32; off > 0; off >>= 1) e_acc += __shfl_down(e_acc, off, 64);
    __shared__ double ws4[4];
    if ((threadIdx.x & 63) == 0) ws4[threadIdx.x >> 6] = e_acc;
    __syncthreads();
    if (threadIdx.x == 0) atomicAdd(energy_ws, ws4[0] + ws4[1] + ws4[2] + ws4[3]);
}

__global__ void __launch_bounds__(256) lj_scrub_kernel(float* __restrict__ buf, int n) {
    int idx = blockIdx.x * blockDim.x + threadIdx.x;
    int stride = gridDim.x * blockDim.x;
    for (int k = idx; k < n; k += stride) buf[k] = scrub_nonfinite(buf[k]);
}

__global__ void lj_finalize_kernel(float* __restrict__ out, const double* __restrict__ ews) {
    out[0] = scrub_nonfinite((float)(0.5 * *ews));
}

extern "C" void kernel_launch(void* const* d_in, const int* in_sizes, int n_in,
                              void* d_out, int out_size, void* d_ws, size_t ws_size,
                              hipStream_t stream) {
    const float* positions = (const float*)d_in[0];
    const float* cell      = (const float*)d_in[1];
    const int*   map_i     = (const int*)d_in[2];
    const int*   map_j     = map_i + N_PAIRS;
    const float* shifts    = (const float*)d_in[3];

    float*  out    = (float*)d_out;
    float*  forces = out + 1;
    double* ews    = (double*)d_ws;
    v4f*    pos4   = (v4f*)((char*)d_ws + 64);

    // pick smallest chunk count whose buffers fit the workspace
    int C = 0;
    {
        const int cands[7] = {1, 2, 4, 8, 16, 32, 64};
        for (int ci = 0; ci < 7; ++ci) {
            const int c = cands[ci];
            const size_t gc = G_TOTAL / c;
            const size_t need = 64 + (size_t)N_ATOMS * 16
                              + gc * NB * 4              // cnts
                              + gc * NB * CAPBB * 16;    // records
            if (need <= ws_size) { C = c; break; }
        }
    }

    if (C > 0) {
        const int gc = G_TOTAL / C;
        const int pc = N_PAIRS / C;
        u32* cnts    = (u32*)((char*)d_ws + 64 + (size_t)N_ATOMS * 16);
        v4u* records = (v4u*)((char*)cnts + (size_t)gc * NB * 4);

        lj_prep_kernel<<<N_ATOMS / 256, 256, 0, stream>>>(positions, pos4, forces, ews);
        for (int c = 0; c < C; ++c) {
            lj_scatter_kernel<<<gc, SC_THREADS, 0, stream>>>(
                pos4, cell, map_i, map_j, shifts, records, cnts, c * pc, gc, ews);
            lj_accum_kernel<<<NB, ACC_THREADS, 0, stream>>>(records, cnts, gc, forces);
        }
        lj_scrub_kernel<<<1024, 256, 0, stream>>>(forces, FCOMP);
    } else {
        lj_zero_kernel<<<2048, 256, 0, stream>>>(forces, FCOMP, ews);
        lj_pair_direct_kernel<<<N_PAIRS / 4 / 256, 256, 0, stream>>>(
            positions, cell, map_i, map_j, shifts, forces, ews);
        lj_scrub_kernel<<<1024, 256, 0, stream>>>(forces, FCOMP);
    }
    lj_finalize_kernel<<<1, 1, 0, stream>>>(out, ews);
}

// Round 13
// 444.628 us; speedup vs baseline: 1.0432x; 1.0432x over previous
//
#include <hip/hip_runtime.h>

#define N_ATOMS 262144
#define N_PAIRS 16777216
#define FCOMP (N_ATOMS * 3)

#define NB      256            // buckets (atom >> 10)
#define BSHIFT  10
#define ALOCAL  (N_ATOMS / NB) // 1024 atoms per bucket
#define CAPBB   32             // record slots per (block,bucket)
#define SC_THREADS 256
#define NPT     32             // pairs per scatter thread
#define PPB     (SC_THREADS * NPT)   // 8192 pairs per scatter block
#define G_TOTAL (N_PAIRS / PPB)      // 2048 scatter blocks total
#define LLIST_CAP 3072         // LDS record list (mean 2392, +10 sigma)
#define ACC_THREADS 1024

typedef int          v4i __attribute__((ext_vector_type(4)));
typedef float        v4f __attribute__((ext_vector_type(4)));
typedef unsigned int u32;
typedef u32          v4u __attribute__((ext_vector_type(4)));

// d_out layout: out[0] = energy, out[1 + 3*a + k] = force[a][k]
// d_ws layout:  [0..63]  double energy accumulator
//               [64..]   pos4 v4f[N_ATOMS] (4 MB)
//               [+4MB]   cnts u32[G_chunk*NB]; then records v4u[G_chunk*NB*CAPBB]

__device__ __forceinline__ void atomic_add_f32(float* addr, float v) {
    unsafeAtomicAdd(addr, v);
}
__device__ __forceinline__ float scrub_nonfinite(float x) {
    return ((__float_as_uint(x) & 0x7f800000u) == 0x7f800000u) ? 0.0f : x;
}

// prep: pad positions to float4; optionally zero forces (multi-chunk path).
__global__ void __launch_bounds__(256) lj_prep_kernel(
    const float* __restrict__ pos, v4f* __restrict__ pos4,
    float* __restrict__ forces, int zero_forces, double* __restrict__ ews)
{
    const int a = blockIdx.x * blockDim.x + threadIdx.x;
    if (a < N_ATOMS) {
        v4f p = {pos[3 * a + 0], pos[3 * a + 1], pos[3 * a + 2], 0.0f};
        pos4[a] = p;
        if (zero_forces) {
            forces[3 * a + 0] = 0.0f;
            forces[3 * a + 1] = 0.0f;
            forces[3 * a + 2] = 0.0f;
        }
    }
    if (a == 0) *ews = 0.0;
}

// ---------- scatter: r7 two-pass LDS-list structure + nt streams ----------
// Pass 1: compute pairs, append in-cutoff records to LDS list (LDS atomics),
// count per-bucket histogram. Pass 2: flush list to per-(block,bucket) global
// sub-regions with nt stores (coalesced-ish, no L2 write-allocate so pos4
// stays L2-resident). Stream loads (mapping/shifts) nontemporal for the same
// reason. The 33.5M random pos4 gathers sit on the measured device wall of
// ~100 G lines/s (r7..r12: six structures, all 320-352 us).
__global__ void __launch_bounds__(SC_THREADS) lj_scatter_kernel(
    const v4f* __restrict__ pos4,
    const float* __restrict__ cell,
    const int* __restrict__ map_i,
    const int* __restrict__ map_j,
    const float* __restrict__ shifts,
    v4u* __restrict__ records,
    u32* __restrict__ cnts,
    int pair_base, int g_count,
    double* __restrict__ energy_ws)
{
    __shared__ u32 hist[NB];
    __shared__ u32 nlist;
    __shared__ v4u list[LLIST_CAP];            // 48 KB
    __shared__ double wave_sums[SC_THREADS / 64];

    const int tid = threadIdx.x;
    const int g   = blockIdx.x;
    if (tid < NB) hist[tid] = 0;
    if (tid == 0) nlist = 0;
    __syncthreads();

    const float c00 = cell[0], c01 = cell[1], c02 = cell[2];
    const float c10 = cell[3], c11 = cell[4], c12 = cell[5];
    const float c20 = cell[6], c21 = cell[7], c22 = cell[8];

    double e_acc = 0.0;

    auto do_pair = [&](int i, int j, float sx, float sy, float sz) {
        const float shx = sx * c00 + sy * c10 + sz * c20;
        const float shy = sx * c01 + sy * c11 + sz * c21;
        const float shz = sx * c02 + sy * c12 + sz * c22;
        const v4f Pi = pos4[i];
        const v4f Pj = pos4[j];
        const float dx = Pj.x - Pi.x + shx;
        const float dy = Pj.y - Pi.y + shy;
        const float dz = Pj.z - Pi.z + shz;
        const float r2 = dx * dx + dy * dy + dz * dz;
        if (r2 < 6.25f) {
            const float inv_r2 = 1.0f / r2;
            const float sr6  = inv_r2 * inv_r2 * inv_r2;
            const float sr12 = sr6 * sr6;
            e_acc += (double)scrub_nonfinite(4.0f * (sr12 - sr6));
            const float pf = 24.0f * inv_r2 * (2.0f * sr12 - sr6);
            const float fx = scrub_nonfinite(pf * dx);
            const float fy = scrub_nonfinite(pf * dy);
            const float fz = scrub_nonfinite(pf * dz);
            const u32 idx = atomicAdd(&nlist, 2u);   // always even
            if (idx + 1 < LLIST_CAP) {
                v4u ri = {(u32)i, __float_as_uint(-fx), __float_as_uint(-fy), __float_as_uint(-fz)};
                v4u rj = {(u32)j, __float_as_uint( fx), __float_as_uint( fy), __float_as_uint( fz)};
                list[idx]     = ri;
                list[idx + 1] = rj;
                atomicAdd(&hist[((u32)i) >> BSHIFT], 1u);
                atomicAdd(&hist[((u32)j) >> BSHIFT], 1u);
            }
        }
    };

    const int base4 = pair_base / 4;
    const v4i* mi4 = (const v4i*)map_i;
    const v4i* mj4 = (const v4i*)map_j;
    const v4f* sh4 = (const v4f*)shifts;
    #pragma unroll
    for (int s = 0; s < NPT / 4; ++s) {
        const int e = base4 + (s * g_count + g) * SC_THREADS + tid;
        const v4i mi = __builtin_nontemporal_load(mi4 + e);
        const v4i mj = __builtin_nontemporal_load(mj4 + e);
        const v4f sa = __builtin_nontemporal_load(sh4 + 3 * e + 0);
        const v4f sb = __builtin_nontemporal_load(sh4 + 3 * e + 1);
        const v4f sc = __builtin_nontemporal_load(sh4 + 3 * e + 2);
        do_pair(mi.x, mj.x, sa.x, sa.y, sa.z);
        do_pair(mi.y, mj.y, sa.w, sb.x, sb.y);
        do_pair(mi.z, mj.z, sb.z, sb.w, sc.x);
        do_pair(mi.w, mj.w, sc.y, sc.z, sc.w);
    }
    __syncthreads();

    // publish per-bucket counts; reset hist as pass-2 cursor
    if (tid < NB) {
        const u32 c = hist[tid];
        cnts[(size_t)g * NB + tid] = (c < CAPBB) ? c : (u32)CAPBB;
        hist[tid] = 0;
    }
    __syncthreads();

    // pass 2: distribute LDS list into per-(block,bucket) global sub-regions
    const size_t rec_base = (size_t)g * NB * CAPBB;
    const u32 n = (nlist < (u32)LLIST_CAP) ? nlist : (u32)LLIST_CAP;
    for (u32 t = tid; t < n; t += SC_THREADS) {
        const v4u rec = list[t];
        const u32 b = rec.x >> BSHIFT;
        const u32 slot = atomicAdd(&hist[b], 1u);
        if (slot < CAPBB)
            __builtin_nontemporal_store(rec, &records[rec_base + (size_t)b * CAPBB + slot]);
    }

    // energy reduce
    for (int off = 32; off > 0; off >>= 1)
        e_acc += __shfl_down(e_acc, off, 64);
    const int lane = tid & 63, wid = tid >> 6;
    if (lane == 0) wave_sums[wid] = e_acc;
    __syncthreads();
    if (tid == 0) {
        double s = 0.0;
        for (int w = 0; w < SC_THREADS / 64; ++w) s += wave_sums[w];
        atomicAdd(energy_ws, s);
    }
}

// ---------- accumulate: block b owns atoms [b*1024, (b+1)*1024) ----------
// overwrite=1 (single-chunk): forces = scrub(facc)  (no pre-zero, no scrub pass)
// write_energy=1: block 0 also finalizes out[0].
__global__ void __launch_bounds__(ACC_THREADS) lj_accum_kernel(
    const v4u* __restrict__ records,
    const u32* __restrict__ cnts,
    int g_count,
    float* __restrict__ forces,
    int overwrite,
    int write_energy,
    const double* __restrict__ ews,
    float* __restrict__ out)
{
    __shared__ float facc[ALOCAL * 3];   // 12 KB
    __shared__ u32 lcnt[G_TOTAL];        // 8 KB (first g_count used)
    const int b = blockIdx.x;
    const int tid = threadIdx.x;

    for (int t = tid; t < ALOCAL * 3; t += ACC_THREADS) facc[t] = 0.0f;
    for (int t = tid; t < g_count; t += ACC_THREADS) lcnt[t] = cnts[(size_t)t * NB + b];
    __syncthreads();

    const int total = g_count * CAPBB;
    for (int r = tid; r < total; r += ACC_THREADS) {
        const int g = r >> 5;       // CAPBB = 32
        const int k = r & (CAPBB - 1);
        if ((u32)k < lcnt[g]) {
            const v4u rec = __builtin_nontemporal_load(&records[((size_t)g * NB + b) * CAPBB + k]);
            const u32 al = rec.x & (ALOCAL - 1);
            atomicAdd(&facc[al * 3 + 0], __uint_as_float(rec.y));
            atomicAdd(&facc[al * 3 + 1], __uint_as_float(rec.z));
            atomicAdd(&facc[al * 3 + 2], __uint_as_float(rec.w));
        }
    }
    __syncthreads();

    const int fbase = (b << BSHIFT) * 3;
    if (overwrite) {
        for (int t = tid; t < ALOCAL * 3; t += ACC_THREADS)
            forces[fbase + t] = scrub_nonfinite(facc[t]);
    } else {
        for (int t = tid; t < ALOCAL * 3; t += ACC_THREADS)
            forces[fbase + t] += facc[t];
    }
    if (write_energy && b == 0 && tid == 0)
        out[0] = scrub_nonfinite((float)(0.5 * *ews));
}

// ---------- fallback path (proven round-2 style, direct atomics) ----------
__global__ void __launch_bounds__(256) lj_zero_kernel(float* __restrict__ buf, int n,
                                                      double* __restrict__ ews) {
    int idx = blockIdx.x * blockDim.x + threadIdx.x;
    int stride = gridDim.x * blockDim.x;
    for (int k = idx; k < n; k += stride) buf[k] = 0.0f;
    if (idx == 0) *ews = 0.0;
}

__global__ void __launch_bounds__(256) lj_pair_direct_kernel(
    const float* __restrict__ pos,
    const float* __restrict__ cell,
    const int* __restrict__ map_i,
    const int* __restrict__ map_j,
    const float* __restrict__ shifts,
    float* __restrict__ forces,
    double* __restrict__ energy_ws)
{
    const float c00 = cell[0], c01 = cell[1], c02 = cell[2];
    const float c10 = cell[3], c11 = cell[4], c12 = cell[5];
    const float c20 = cell[6], c21 = cell[7], c22 = cell[8];
    double e_acc = 0.0;
    const int t = blockIdx.x * blockDim.x + threadIdx.x;
    const v4i mi = ((const v4i*)map_i)[t];
    const v4i mj = ((const v4i*)map_j)[t];
    const v4f sa = ((const v4f*)shifts)[3 * t + 0];
    const v4f sb = ((const v4f*)shifts)[3 * t + 1];
    const v4f sc = ((const v4f*)shifts)[3 * t + 2];
    auto body = [&](int i, int j, float sx, float sy, float sz) {
        const float shx = sx * c00 + sy * c10 + sz * c20;
        const float shy = sx * c01 + sy * c11 + sz * c21;
        const float shz = sx * c02 + sy * c12 + sz * c22;
        const float dx = pos[3*j]   - pos[3*i]   + shx;
        const float dy = pos[3*j+1] - pos[3*i+1] + shy;
        const float dz = pos[3*j+2] - pos[3*i+2] + shz;
        const float r2 = dx*dx + dy*dy + dz*dz;
        if (r2 < 6.25f) {
            const float inv_r2 = 1.0f / r2;
            const float sr6 = inv_r2*inv_r2*inv_r2, sr12 = sr6*sr6;
            e_acc += (double)scrub_nonfinite(4.0f * (sr12 - sr6));
            const float pf = 24.0f * inv_r2 * (2.0f * sr12 - sr6);
            const float fx = scrub_nonfinite(pf*dx), fy = scrub_nonfinite(pf*dy), fz = scrub_nonfinite(pf*dz);
            atomic_add_f32(&forces[3*i+0], -fx); atomic_add_f32(&forces[3*i+1], -fy); atomic_add_f32(&forces[3*i+2], -fz);
            atomic_add_f32(&forces[3*j+0],  fx); atomic_add_f32(&forces[3*j+1],  fy); atomic_add_f32(&forces[3*j+2],  fz);
        }
    };
    body(mi.x, mj.x, sa.x, sa.y, sa.z);
    body(mi.y, mj.y, sa.w, sb.x, sb.y);
    body(mi.z, mj.z, sb.z, sb.w, sc.x);
    body(mi.w, mj.w, sc.y, sc.z, sc.w);
    for (int off = 32; off > 0; off >>= 1) e_acc += __shfl_down(e_acc, off, 64);
    __shared__ double ws4[4];
    if ((threadIdx.x & 63) == 0) ws4[threadIdx.x >> 6] = e_acc;
    __syncthreads();
    if (threadIdx.x == 0) atomicAdd(energy_ws, ws4[0] + ws4[1] + ws4[2] + ws4[3]);
}

__global__ void __launch_bounds__(256) lj_scrub_kernel(float* __restrict__ buf, int n) {
    int idx = blockIdx.x * blockDim.x + threadIdx.x;
    int stride = gridDim.x * blockDim.x;
    for (int k = idx; k < n; k += stride) buf[k] = scrub_nonfinite(buf[k]);
}

__global__ void lj_finalize_kernel(float* __restrict__ out, const double* __restrict__ ews) {
    out[0] = scrub_nonfinite((float)(0.5 * *ews));
}

extern "C" void kernel_launch(void* const* d_in, const int* in_sizes, int n_in,
                              void* d_out, int out_size, void* d_ws, size_t ws_size,
                              hipStream_t stream) {
    const float* positions = (const float*)d_in[0];
    const float* cell      = (const float*)d_in[1];
    const int*   map_i     = (const int*)d_in[2];
    const int*   map_j     = map_i + N_PAIRS;
    const float* shifts    = (const float*)d_in[3];

    float*  out    = (float*)d_out;
    float*  forces = out + 1;
    double* ews    = (double*)d_ws;
    v4f*    pos4   = (v4f*)((char*)d_ws + 64);

    // pick smallest chunk count whose buffers fit the workspace
    int C = 0;
    {
        const int cands[6] = {1, 2, 4, 8, 16, 32};
        for (int ci = 0; ci < 6; ++ci) {
            const int c = cands[ci];
            const size_t gc = G_TOTAL / c;
            const size_t need = 64 + (size_t)N_ATOMS * 16
                              + gc * NB * 4              // cnts
                              + gc * NB * CAPBB * 16;    // records
            if (need <= ws_size) { C = c; break; }
        }
    }

    if (C > 0) {
        const int gc = G_TOTAL / C;
        const int pc = N_PAIRS / C;
        u32* cnts    = (u32*)((char*)d_ws + 64 + (size_t)N_ATOMS * 16);
        v4u* records = (v4u*)((char*)cnts + (size_t)gc * NB * 4);
        const int single = (C == 1);

        lj_prep_kernel<<<N_ATOMS / 256, 256, 0, stream>>>(
            positions, pos4, forces, single ? 0 : 1, ews);
        for (int c = 0; c < C; ++c) {
            lj_scatter_kernel<<<gc, SC_THREADS, 0, stream>>>(
                pos4, cell, map_i, map_j, shifts, records, cnts, c * pc, gc, ews);
            const int last = (c == C - 1);
            lj_accum_kernel<<<NB, ACC_THREADS, 0, stream>>>(
                records, cnts, gc, forces,
                single ? 1 : 0,          // overwrite only when one chunk
                last ? 1 : 0, ews, out); // finalize energy on the last chunk
        }
        if (!single)
            lj_scrub_kernel<<<1024, 256, 0, stream>>>(forces, FCOMP);
    } else {
        lj_zero_kernel<<<2048, 256, 0, stream>>>(forces, FCOMP, ews);
        lj_pair_direct_kernel<<<N_PAIRS / 4 / 256, 256, 0, stream>>>(
            positions, cell, map_i, map_j, shifts, forces, ews);
        lj_scrub_kernel<<<1024, 256, 0, stream>>>(forces, FCOMP);
        lj_finalize_kernel<<<1, 1, 0, stream>>>(out, ews);
    }
}

// Round 14
// 379.572 us; speedup vs baseline: 1.2220x; 1.1714x over previous
//
#include <hip/hip_runtime.h>

#define N_ATOMS 262144
#define N_PAIRS 16777216
#define FCOMP (N_ATOMS * 3)

#define NB      256            // buckets (atom >> 10)
#define BSHIFT  10
#define ALOCAL  (N_ATOMS / NB) // 1024 atoms per bucket
#define CAPBB   32             // record slots per (block,bucket)
#define SC_THREADS 256
#define NPT     32             // pairs per scatter thread
#define PPB     (SC_THREADS * NPT)   // 8192 pairs per scatter block
#define G_TOTAL (N_PAIRS / PPB)      // 2048 scatter blocks total
#define LLIST_CAP 3072         // LDS record list (mean 2392, +10 sigma)
#define ACC_THREADS 1024

typedef int          v4i __attribute__((ext_vector_type(4)));
typedef float        v4f __attribute__((ext_vector_type(4)));
typedef unsigned int u32;
typedef u32          v4u __attribute__((ext_vector_type(4)));

// d_out layout: out[0] = energy, out[1 + 3*a + k] = force[a][k]
// d_ws layout:  [0..63]  double energy accumulator
//               [64..]   pos4 v4f[N_ATOMS] (4 MB)
//               [+4MB]   cnts u32[G_chunk*NB]; then records v4u[G_chunk*NB*CAPBB]

__device__ __forceinline__ void atomic_add_f32(float* addr, float v) {
    unsafeAtomicAdd(addr, v);
}
__device__ __forceinline__ float scrub_nonfinite(float x) {
    return ((__float_as_uint(x) & 0x7f800000u) == 0x7f800000u) ? 0.0f : x;
}

// prep: pad positions to float4; optionally zero forces (multi-chunk path).
__global__ void __launch_bounds__(256) lj_prep_kernel(
    const float* __restrict__ pos, v4f* __restrict__ pos4,
    float* __restrict__ forces, int zero_forces, double* __restrict__ ews)
{
    const int a = blockIdx.x * blockDim.x + threadIdx.x;
    if (a < N_ATOMS) {
        v4f p = {pos[3 * a + 0], pos[3 * a + 1], pos[3 * a + 2], 0.0f};
        pos4[a] = p;
        if (zero_forces) {
            forces[3 * a + 0] = 0.0f;
            forces[3 * a + 1] = 0.0f;
            forces[3 * a + 2] = 0.0f;
        }
    }
    if (a == 0) *ews = 0.0;
}

// ---------- scatter: exact r7 structure (fastest measured: 322 us) ----------
// Plain (cached) stream loads and stores — r13's nt variants cost +37 us at
// this 3-blocks/CU occupancy. Two-pass: (1) compute + append to LDS list,
// (2) flush to per-(block,bucket) global sub-regions. The 33.5M random pos4
// gathers sit on the measured device wall of ~100 G random-lines/s
// (r7..r13: seven structures, all 320-360 us).
__global__ void __launch_bounds__(SC_THREADS) lj_scatter_kernel(
    const v4f* __restrict__ pos4,
    const float* __restrict__ cell,
    const int* __restrict__ map_i,
    const int* __restrict__ map_j,
    const float* __restrict__ shifts,
    v4u* __restrict__ records,
    u32* __restrict__ cnts,
    int pair_base, int g_count,
    double* __restrict__ energy_ws)
{
    __shared__ u32 hist[NB];
    __shared__ u32 nlist;
    __shared__ v4u list[LLIST_CAP];            // 48 KB
    __shared__ double wave_sums[SC_THREADS / 64];

    const int tid = threadIdx.x;
    const int g   = blockIdx.x;
    if (tid < NB) hist[tid] = 0;
    if (tid == 0) nlist = 0;
    __syncthreads();

    const float c00 = cell[0], c01 = cell[1], c02 = cell[2];
    const float c10 = cell[3], c11 = cell[4], c12 = cell[5];
    const float c20 = cell[6], c21 = cell[7], c22 = cell[8];

    double e_acc = 0.0;

    auto do_pair = [&](int i, int j, float sx, float sy, float sz) {
        const float shx = sx * c00 + sy * c10 + sz * c20;
        const float shy = sx * c01 + sy * c11 + sz * c21;
        const float shz = sx * c02 + sy * c12 + sz * c22;
        const v4f Pi = pos4[i];
        const v4f Pj = pos4[j];
        const float dx = Pj.x - Pi.x + shx;
        const float dy = Pj.y - Pi.y + shy;
        const float dz = Pj.z - Pi.z + shz;
        const float r2 = dx * dx + dy * dy + dz * dz;
        if (r2 < 6.25f) {
            const float inv_r2 = 1.0f / r2;
            const float sr6  = inv_r2 * inv_r2 * inv_r2;
            const float sr12 = sr6 * sr6;
            e_acc += (double)scrub_nonfinite(4.0f * (sr12 - sr6));
            const float pf = 24.0f * inv_r2 * (2.0f * sr12 - sr6);
            const float fx = scrub_nonfinite(pf * dx);
            const float fy = scrub_nonfinite(pf * dy);
            const float fz = scrub_nonfinite(pf * dz);
            const u32 idx = atomicAdd(&nlist, 2u);   // always even
            if (idx + 1 < LLIST_CAP) {
                v4u ri = {(u32)i, __float_as_uint(-fx), __float_as_uint(-fy), __float_as_uint(-fz)};
                v4u rj = {(u32)j, __float_as_uint( fx), __float_as_uint( fy), __float_as_uint( fz)};
                list[idx]     = ri;
                list[idx + 1] = rj;
                atomicAdd(&hist[((u32)i) >> BSHIFT], 1u);
                atomicAdd(&hist[((u32)j) >> BSHIFT], 1u);
            }
        }
    };

    const int base4 = pair_base / 4;
    #pragma unroll
    for (int s = 0; s < NPT / 4; ++s) {
        const int e = base4 + (s * g_count + g) * SC_THREADS + tid;
        const v4i mi = ((const v4i*)map_i)[e];
        const v4i mj = ((const v4i*)map_j)[e];
        const v4f sa = ((const v4f*)shifts)[3 * e + 0];
        const v4f sb = ((const v4f*)shifts)[3 * e + 1];
        const v4f sc = ((const v4f*)shifts)[3 * e + 2];
        do_pair(mi.x, mj.x, sa.x, sa.y, sa.z);
        do_pair(mi.y, mj.y, sa.w, sb.x, sb.y);
        do_pair(mi.z, mj.z, sb.z, sb.w, sc.x);
        do_pair(mi.w, mj.w, sc.y, sc.z, sc.w);
    }
    __syncthreads();

    // publish per-bucket counts; reset hist as pass-2 cursor
    if (tid < NB) {
        const u32 c = hist[tid];
        cnts[(size_t)g * NB + tid] = (c < CAPBB) ? c : (u32)CAPBB;
        hist[tid] = 0;
    }
    __syncthreads();

    // pass 2: distribute LDS list into per-(block,bucket) global sub-regions
    const size_t rec_base = (size_t)g * NB * CAPBB;
    const u32 n = (nlist < (u32)LLIST_CAP) ? nlist : (u32)LLIST_CAP;
    for (u32 t = tid; t < n; t += SC_THREADS) {
        const v4u rec = list[t];
        const u32 b = rec.x >> BSHIFT;
        const u32 slot = atomicAdd(&hist[b], 1u);
        if (slot < CAPBB)
            records[rec_base + (size_t)b * CAPBB + slot] = rec;
    }

    // energy reduce
    for (int off = 32; off > 0; off >>= 1)
        e_acc += __shfl_down(e_acc, off, 64);
    const int lane = tid & 63, wid = tid >> 6;
    if (lane == 0) wave_sums[wid] = e_acc;
    __syncthreads();
    if (tid == 0) {
        double s = 0.0;
        for (int w = 0; w < SC_THREADS / 64; ++w) s += wave_sums[w];
        atomicAdd(energy_ws, s);
    }
}

// ---------- accumulate: block b owns atoms [b*1024, (b+1)*1024) ----------
// overwrite=1 (single-chunk): forces = scrub(facc)  (no pre-zero, no scrub pass)
// write_energy=1: block 0 also finalizes out[0].
__global__ void __launch_bounds__(ACC_THREADS) lj_accum_kernel(
    const v4u* __restrict__ records,
    const u32* __restrict__ cnts,
    int g_count,
    float* __restrict__ forces,
    int overwrite,
    int write_energy,
    const double* __restrict__ ews,
    float* __restrict__ out)
{
    __shared__ float facc[ALOCAL * 3];   // 12 KB
    __shared__ u32 lcnt[G_TOTAL];        // 8 KB (first g_count used)
    const int b = blockIdx.x;
    const int tid = threadIdx.x;

    for (int t = tid; t < ALOCAL * 3; t += ACC_THREADS) facc[t] = 0.0f;
    for (int t = tid; t < g_count; t += ACC_THREADS) lcnt[t] = cnts[(size_t)t * NB + b];
    __syncthreads();

    const int total = g_count * CAPBB;
    for (int r = tid; r < total; r += ACC_THREADS) {
        const int g = r >> 5;       // CAPBB = 32
        const int k = r & (CAPBB - 1);
        if ((u32)k < lcnt[g]) {
            const v4u rec = records[((size_t)g * NB + b) * CAPBB + k];
            const u32 al = rec.x & (ALOCAL - 1);
            atomicAdd(&facc[al * 3 + 0], __uint_as_float(rec.y));
            atomicAdd(&facc[al * 3 + 1], __uint_as_float(rec.z));
            atomicAdd(&facc[al * 3 + 2], __uint_as_float(rec.w));
        }
    }
    __syncthreads();

    const int fbase = (b << BSHIFT) * 3;
    if (overwrite) {
        for (int t = tid; t < ALOCAL * 3; t += ACC_THREADS)
            forces[fbase + t] = scrub_nonfinite(facc[t]);
    } else {
        for (int t = tid; t < ALOCAL * 3; t += ACC_THREADS)
            forces[fbase + t] += facc[t];
    }
    if (write_energy && b == 0 && tid == 0)
        out[0] = scrub_nonfinite((float)(0.5 * *ews));
}

// ---------- fallback path (proven round-2 style, direct atomics) ----------
__global__ void __launch_bounds__(256) lj_zero_kernel(float* __restrict__ buf, int n,
                                                      double* __restrict__ ews) {
    int idx = blockIdx.x * blockDim.x + threadIdx.x;
    int stride = gridDim.x * blockDim.x;
    for (int k = idx; k < n; k += stride) buf[k] = 0.0f;
    if (idx == 0) *ews = 0.0;
}

__global__ void __launch_bounds__(256) lj_pair_direct_kernel(
    const float* __restrict__ pos,
    const float* __restrict__ cell,
    const int* __restrict__ map_i,
    const int* __restrict__ map_j,
    const float* __restrict__ shifts,
    float* __restrict__ forces,
    double* __restrict__ energy_ws)
{
    const float c00 = cell[0], c01 = cell[1], c02 = cell[2];
    const float c10 = cell[3], c11 = cell[4], c12 = cell[5];
    const float c20 = cell[6], c21 = cell[7], c22 = cell[8];
    double e_acc = 0.0;
    const int t = blockIdx.x * blockDim.x + threadIdx.x;
    const v4i mi = ((const v4i*)map_i)[t];
    const v4i mj = ((const v4i*)map_j)[t];
    const v4f sa = ((const v4f*)shifts)[3 * t + 0];
    const v4f sb = ((const v4f*)shifts)[3 * t + 1];
    const v4f sc = ((const v4f*)shifts)[3 * t + 2];
    auto body = [&](int i, int j, float sx, float sy, float sz) {
        const float shx = sx * c00 + sy * c10 + sz * c20;
        const float shy = sx * c01 + sy * c11 + sz * c21;
        const float shz = sx * c02 + sy * c12 + sz * c22;
        const float dx = pos[3*j]   - pos[3*i]   + shx;
        const float dy = pos[3*j+1] - pos[3*i+1] + shy;
        const float dz = pos[3*j+2] - pos[3*i+2] + shz;
        const float r2 = dx*dx + dy*dy + dz*dz;
        if (r2 < 6.25f) {
            const float inv_r2 = 1.0f / r2;
            const float sr6 = inv_r2*inv_r2*inv_r2, sr12 = sr6*sr6;
            e_acc += (double)scrub_nonfinite(4.0f * (sr12 - sr6));
            const float pf = 24.0f * inv_r2 * (2.0f * sr12 - sr6);
            const float fx = scrub_nonfinite(pf*dx), fy = scrub_nonfinite(pf*dy), fz = scrub_nonfinite(pf*dz);
            atomic_add_f32(&forces[3*i+0], -fx); atomic_add_f32(&forces[3*i+1], -fy); atomic_add_f32(&forces[3*i+2], -fz);
            atomic_add_f32(&forces[3*j+0],  fx); atomic_add_f32(&forces[3*j+1],  fy); atomic_add_f32(&forces[3*j+2],  fz);
        }
    };
    body(mi.x, mj.x, sa.x, sa.y, sa.z);
    body(mi.y, mj.y, sa.w, sb.x, sb.y);
    body(mi.z, mj.z, sb.z, sb.w, sc.x);
    body(mi.w, mj.w, sc.y, sc.z, sc.w);
    for (int off = 32; off > 0; off >>= 1) e_acc += __shfl_down(e_acc, off, 64);
    __shared__ double ws4[4];
    if ((threadIdx.x & 63) == 0) ws4[threadIdx.x >> 6] = e_acc;
    __syncthreads();
    if (threadIdx.x == 0) atomicAdd(energy_ws, ws4[0] + ws4[1] + ws4[2] + ws4[3]);
}

__global__ void __launch_bounds__(256) lj_scrub_kernel(float* __restrict__ buf, int n) {
    int idx = blockIdx.x * blockDim.x + threadIdx.x;
    int stride = gridDim.x * blockDim.x;
    for (int k = idx; k < n; k += stride) buf[k] = scrub_nonfinite(buf[k]);
}

__global__ void lj_finalize_kernel(float* __restrict__ out, const double* __restrict__ ews) {
    out[0] = scrub_nonfinite((float)(0.5 * *ews));
}

extern "C" void kernel_launch(void* const* d_in, const int* in_sizes, int n_in,
                              void* d_out, int out_size, void* d_ws, size_t ws_size,
                              hipStream_t stream) {
    const float* positions = (const float*)d_in[0];
    const float* cell      = (const float*)d_in[1];
    const int*   map_i     = (const int*)d_in[2];
    const int*   map_j     = map_i + N_PAIRS;
    const float* shifts    = (const float*)d_in[3];

    float*  out    = (float*)d_out;
    float*  forces = out + 1;
    double* ews    = (double*)d_ws;
    v4f*    pos4   = (v4f*)((char*)d_ws + 64);

    // pick smallest chunk count whose buffers fit the workspace
    int C = 0;
    {
        const int cands[6] = {1, 2, 4, 8, 16, 32};
        for (int ci = 0; ci < 6; ++ci) {
            const int c = cands[ci];
            const size_t gc = G_TOTAL / c;
            const size_t need = 64 + (size_t)N_ATOMS * 16
                              + gc * NB * 4              // cnts
                              + gc * NB * CAPBB * 16;    // records
            if (need <= ws_size) { C = c; break; }
        }
    }

    if (C > 0) {
        const int gc = G_TOTAL / C;
        const int pc = N_PAIRS / C;
        u32* cnts    = (u32*)((char*)d_ws + 64 + (size_t)N_ATOMS * 16);
        v4u* records = (v4u*)((char*)cnts + (size_t)gc * NB * 4);
        const int single = (C == 1);

        lj_prep_kernel<<<N_ATOMS / 256, 256, 0, stream>>>(
            positions, pos4, forces, single ? 0 : 1, ews);
        for (int c = 0; c < C; ++c) {
            lj_scatter_kernel<<<gc, SC_THREADS, 0, stream>>>(
                pos4, cell, map_i, map_j, shifts, records, cnts, c * pc, gc, ews);
            const int last = (c == C - 1);
            lj_accum_kernel<<<NB, ACC_THREADS, 0, stream>>>(
                records, cnts, gc, forces,
                single ? 1 : 0,          // overwrite only when one chunk
                last ? 1 : 0, ews, out); // finalize energy on the last chunk
        }
        if (!single)
            lj_scrub_kernel<<<1024, 256, 0, stream>>>(forces, FCOMP);
    } else {
        lj_zero_kernel<<<2048, 256, 0, stream>>>(forces, FCOMP, ews);
        lj_pair_direct_kernel<<<N_PAIRS / 4 / 256, 256, 0, stream>>>(
            positions, cell, map_i, map_j, shifts, forces, ews);
        lj_scrub_kernel<<<1024, 256, 0, stream>>>(forces, FCOMP);
        lj_finalize_kernel<<<1, 1, 0, stream>>>(out, ews);
    }
}